// Round 3
// baseline (156.707 us; speedup 1.0000x reference)
//
#include <hip/hip_runtime.h>
#include <hip/hip_bf16.h>

// CARAFE R9:
//  - k_prep: merged repacks + halo clears (R7, verified).
//  - k_dzmfma: fused down+z GEMM (unchanged, verified).
//  - k_tail: k_encmfma MERGED INTO k_fused_out. Each block computes its own
//    16px x 100ch enc tile via MFMA from a 3x18x64 downT slab staged in LDS
//    (6.75 KB), then softmax + reassembly + pixel shuffle + stores as R7.
//    Deletes the enc HBM round-trip (6.6 MB w + 26 MB r) and one dispatch.
//    R8's z-LDS-staging and XCD swizzle are REVERTED (regressed: occupancy
//    halved; z tap re-reads were L1 hits already).
//  - enc-MFMA accumulation order identical to old k_encmfma -> bitwise same.
// Pipeline: 3 dispatches. N=4, H=W=64, INC=256, CM=64, KUP=5, DELTA=2,
// enc_out=100, OUTC=256.

namespace {
constexpr int kN = 4, kH = 64, kW = 64, kINC = 256, kCM = 64;
constexpr int kENC = 100, kH2 = 128, kW2 = 128, kOUTC = 256;
constexpr int kHW = kH * kW;       // 4096
constexpr int kHW2 = kH2 * kW2;    // 16384
constexpr int kPadW = 66;          // 64 + 1 halo (enc 3x3)
constexpr int kTImg = kPadW * kPadW * kCM;    // 278784 (downT per image)
constexpr int kZPad = 68;          // 64 + 2 halo (reassembly 5x5)
constexpr int kZImg = kZPad * kZPad * kOUTC;  // 1183744 (zT per image)
constexpr int kKP = 108;           // kern LDS pitch (108%32=12 -> 2-way, free)
// k_prep thread-range boundaries (all block-aligned except final tail):
constexpr int kPrepRepackEnc = 9 * 7 * 2 * 512;          // 64512  (252 blocks)
constexpr int kPrepRepackWoz = 8 * 20 * 512;             // 81920  (320 blocks)
constexpr int kPrepHaloZ = 4 * 528 * 16;                 // 33792
constexpr int kPrepHaloD = 4 * 260 * 8;                  // 8320
constexpr int kPrepTotal = kPrepRepackEnc + kPrepRepackWoz + kPrepHaloZ + kPrepHaloD; // 188544
}

typedef __attribute__((ext_vector_type(8))) short short8;   // 8 bf16
typedef __attribute__((ext_vector_type(4))) float floatx4;  // MFMA acc

static __device__ __forceinline__ unsigned short bf16bits(float f) {
  __hip_bfloat16 h = __float2bfloat16(f);
  return *(unsigned short*)&h;
}

// ---------- merged prep: weight repacks + halo clears (one dispatch) ----------
__global__ __launch_bounds__(256) void k_prep(
    const float* __restrict__ we, unsigned short* __restrict__ Aswz,
    const float* __restrict__ wd, const float* __restrict__ wo,
    unsigned short* __restrict__ Awoz,
    float* __restrict__ zT, __hip_bfloat16* __restrict__ downT) {
  const int t = blockIdx.x * 256 + threadIdx.x;
  if (t < kPrepRepackEnc) {
    const int e = t;
    const int j = e & 7, lane = (e >> 3) & 63, kh = (e >> 9) & 1, tm = e >> 10;
    const int mt = tm % 7, tap = tm / 7;
    const int o = mt * 16 + (lane & 15);
    const int ci = kh * 32 + ((lane >> 4) & 3) * 8 + j;
    const float v = (o < kENC) ? we[(size_t)o * 576 + ci * 9 + tap] : 0.f;
    Aswz[e] = bf16bits(v);
  } else if (t < kPrepRepackEnc + kPrepRepackWoz) {
    const int e = t - kPrepRepackEnc;
    const int j = e & 7, lane = (e >> 3) & 63;
    const int rest = e >> 9;
    const int mt = rest % 20, ks = rest / 20;
    const int r = mt * 16 + (lane & 15);
    const int k = ks * 32 + (lane >> 4) * 8 + j;
    const float v = (r < kCM) ? wd[(size_t)r * kINC + k]
                              : wo[(size_t)(r - kCM) * kINC + k];
    Awoz[e] = bf16bits(v);
  } else if (t < kPrepTotal) {
    const int u0 = t - (kPrepRepackEnc + kPrepRepackWoz);
    if (u0 < kPrepHaloZ) {
      const int chunk = u0 & 15, rest = u0 >> 4;
      const int i = rest % 528, n = rest / 528;
      int r, c;
      if (i < 272) { r = i / 68; if (r >= 2) r += 64; c = i % 68; }
      else { const int j = i - 272; r = 2 + (j >> 2); const int cc = j & 3; c = (cc < 2) ? cc : cc + 64; }
      float4* p = (float4*)(zT + (size_t)n * kZImg + ((size_t)r * kZPad + c) * kOUTC) + chunk;
      *p = make_float4(0.f, 0.f, 0.f, 0.f);
    } else {
      const int u = u0 - kPrepHaloZ;
      const int chunk = u & 7, rest = u >> 3;
      const int i = rest % 260, n = rest / 260;
      int r, c;
      if (i < 132) { r = (i / 66) ? 65 : 0; c = i % 66; }
      else { const int j = i - 132; r = 1 + (j >> 1); c = (j & 1) ? 65 : 0; }
      float4* p = (float4*)((char*)downT
                  + ((size_t)n * kTImg + ((size_t)r * kPadW + c) * kCM) * 2) + chunk;
      *p = make_float4(0.f, 0.f, 0.f, 0.f);
    }
  }
}

// ---------- fused down + z GEMM: M=320, K=256, N=16384 (R5, verified) ----------
__global__ __launch_bounds__(256) void k_dzmfma(
    const float* __restrict__ x, const unsigned short* __restrict__ Awoz,
    const float* __restrict__ bd, __hip_bfloat16* __restrict__ downT,
    float* __restrict__ zT) {
  const int b = blockIdx.x;
  const int pt = b & 255, n = b >> 8;
  const int wave = threadIdx.x >> 6, lane = threadIdx.x & 63;
  const int col = lane & 15, quad = lane >> 4;
  const int px = pt * 16 + col;
  const int h = px >> 6, w = px & 63;
  const float* xb = x + (size_t)n * kINC * kHW + px;

  floatx4 acc[5];
#pragma unroll
  for (int m = 0; m < 5; ++m) acc[m] = (floatx4){0.f, 0.f, 0.f, 0.f};

#pragma unroll
  for (int ks = 0; ks < 8; ++ks) {
    float xv[8];
#pragma unroll
    for (int j = 0; j < 8; ++j)
      xv[j] = xb[(size_t)(ks * 32 + quad * 8 + j) * kHW];
    short8 bf;
#pragma unroll
    for (int j = 0; j < 8; ++j) bf[j] = (short)bf16bits(xv[j]);
#pragma unroll
    for (int m = 0; m < 5; ++m) {
      const int wtile = wave * 5 + m;
      const short8 af = *(const short8*)(
          Awoz + ((size_t)(ks * 20 + wtile) * 64 + lane) * 8);
      acc[m] = __builtin_amdgcn_mfma_f32_16x16x32_bf16(af, bf, acc[m], 0, 0, 0);
    }
  }

#pragma unroll
  for (int m = 0; m < 5; ++m) {
    const int wtile = wave * 5 + m;
    const int r0 = wtile * 16 + quad * 4;
    if (wtile < 4) {
      union { unsigned short u[4]; uint2 v; } pk;
#pragma unroll
      for (int rr = 0; rr < 4; ++rr)
        pk.u[rr] = bf16bits(acc[m][rr] + bd[r0 + rr]);
      __hip_bfloat16* dst = downT + (size_t)n * kTImg
                            + ((h + 1) * kPadW + (w + 1)) * kCM + r0;
      *(uint2*)dst = pk.v;
    } else {
      const int o = r0 - kCM;
      float* dst = zT + (size_t)n * kZImg
                   + ((h + 2) * kZPad + (w + 2)) * kOUTC + o;
      *(float4*)dst = make_float4(acc[m][0], acc[m][1], acc[m][2], acc[m][3]);
    }
  }
}

// ---------- fused enc-conv + softmax + reassembly + shuffle + bias (v6) ----------
// 4096 blocks: pt(256) x og(4) x n(4); 256 thr = 4 waves.
// Phase 0: stage downT slab [8 chunk][3 row][18 col] (chunk = 16B of 8 ch;
//   chunk fastest in global -> fully coalesced 128B/8 lanes).
// Phase 1: enc tile via MFMA (M=100 in 7 mt-tiles, N=16 px, K=576 in 18
//   ksteps) -> kernLDS[px][kKP] with bias. Same accumulation order as the
//   old k_encmfma -> bitwise identical enc.
// Phase 2: in-LDS softmax over 25 taps (64 workers).
// Phase 3: 25 taps, direct global z float4 (L1-served) + kern ds_read_b128.
// Phase 4: acc -> LDS transpose (stride-65) -> coalesced float4 stores.
// LDS: kern 6912B + slab 6912B, overlaid by 16640B transpose = 16.6 KB.
__global__ __launch_bounds__(256) void k_tail(
    const float* __restrict__ zT, const __hip_bfloat16* __restrict__ downT,
    const unsigned short* __restrict__ Aswz, const float* __restrict__ be,
    const float* __restrict__ bo, float* __restrict__ out) {
  const int b = blockIdx.x;
  const int pt = b & 255, og = (b >> 8) & 3, n = b >> 10;
  const int tid = threadIdx.x;
  const int wave = tid >> 6, lane = tid & 63;
  const int h = pt >> 2, w0 = (pt & 3) << 4;   // 16-px segment [w0, w0+16)

  __shared__ float lds[4160];                  // 16.6 KB
  float* kernLDS = lds;                        // [16 px][kKP]; 1728 floats
  unsigned short* slab = (unsigned short*)(lds + 1728);  // [8][3][18] x 8 ch

  // --- phase 0: stage downT slab (coalesced: chunk fastest) ---
  {
    const unsigned short* dTg = (const unsigned short*)downT + (size_t)n * kTImg;
#pragma unroll
    for (int it = 0; it < 2; ++it) {
      const int idx = it * 256 + tid;
      if (idx < 432) {
        const int chunk = idx & 7, rowcol = idx >> 3;
        const int row = rowcol / 18, c = rowcol % 18;
        const short8 v = *(const short8*)(
            dTg + (((size_t)(h + row) * kPadW) + (w0 + c)) * kCM + chunk * 8);
        *(short8*)(slab + ((chunk * 54 + row * 18 + c) * 8)) = v;
      }
    }
  }
  __syncthreads();

  // --- phase 1: enc tile via MFMA (same order as k_encmfma) ---
  {
    const int col = lane & 15, quad = lane >> 4;
    const int mt0 = wave * 2;
    const bool has2 = (mt0 + 1) < 7;           // wave 3: only mt=6
    floatx4 acc0 = {0.f, 0.f, 0.f, 0.f}, acc1 = {0.f, 0.f, 0.f, 0.f};
#pragma unroll
    for (int tap = 0; tap < 9; ++tap) {
      const int dh = tap / 3, dw = tap % 3;    // slab row = 1+dh-1+... = dh
#pragma unroll
      for (int kh = 0; kh < 2; ++kh) {
        const short8 bf = *(const short8*)(
            slab + ((kh * 4 + quad) * 54 + dh * 18 + (col + dw)) * 8);
        const short8 a0 = *(const short8*)(
            Aswz + (((size_t)(tap * 7 + mt0) * 2 + kh) * 64 + lane) * 8);
        acc0 = __builtin_amdgcn_mfma_f32_16x16x32_bf16(a0, bf, acc0, 0, 0, 0);
        if (has2) {
          const short8 a1 = *(const short8*)(
              Aswz + (((size_t)(tap * 7 + mt0 + 1) * 2 + kh) * 64 + lane) * 8);
          acc1 = __builtin_amdgcn_mfma_f32_16x16x32_bf16(a1, bf, acc1, 0, 0, 0);
        }
      }
    }
#pragma unroll
    for (int r = 0; r < 4; ++r) {
      const int o = mt0 * 16 + quad * 4 + r;
      if (o < kENC) kernLDS[col * kKP + o] = acc0[r] + be[o];
    }
    if (has2) {
#pragma unroll
      for (int r = 0; r < 4; ++r) {
        const int o = (mt0 + 1) * 16 + quad * 4 + r;
        if (o < kENC) kernLDS[col * kKP + o] = acc1[r] + be[o];
      }
    }
  }
  __syncthreads();

  // --- phase 2: in-LDS softmax over 25 taps, worker = (px, d) ---
  if (tid < 64) {
    const int p = tid >> 2, d = tid & 3;
    float* kb = kernLDS + p * kKP + d;         // taps at stride 4 floats
    float m = -1e30f;
#pragma unroll
    for (int k = 0; k < 25; ++k) m = fmaxf(m, kb[k * 4]);
    float s = 0.f;
#pragma unroll
    for (int k = 0; k < 25; ++k) {
      const float e = __expf(kb[k * 4] - m);
      kb[k * 4] = e;
      s += e;
    }
    const float inv = 1.f / s;
#pragma unroll
    for (int k = 0; k < 25; ++k) kb[k * 4] *= inv;
  }
  __syncthreads();

  // --- phase 3: 25 taps, direct global z (L1-served) ---
  const int oc = lane & 15, pxi = lane >> 4;
  const int px_l = wave * 4 + pxi;             // [0,16)
  const int w = w0 + px_l;
  const int o_l = oc * 4;                      // [0,64) step 4
  const float* zb = zT + (size_t)n * kZImg + og * 64 + o_l;
  const float* kp = kernLDS + px_l * kKP;
  float acc[4][4] = {};                        // [oi][d]
#pragma unroll
  for (int tap = 0; tap < 25; ++tap) {
    const int kh = tap / 5, kw = tap % 5;      // z idx: (h+2 + kh-2) = h+kh
    const float4 zf = *(const float4*)(
        zb + ((size_t)(h + kh) * kZPad + (w + kw)) * kOUTC);
    const float4 kf = *(const float4*)(kp + tap * 4);
    acc[0][0] += zf.x * kf.x; acc[0][1] += zf.x * kf.y; acc[0][2] += zf.x * kf.z; acc[0][3] += zf.x * kf.w;
    acc[1][0] += zf.y * kf.x; acc[1][1] += zf.y * kf.y; acc[1][2] += zf.y * kf.z; acc[1][3] += zf.y * kf.w;
    acc[2][0] += zf.z * kf.x; acc[2][1] += zf.z * kf.y; acc[2][2] += zf.z * kf.z; acc[2][3] += zf.z * kf.w;
    acc[3][0] += zf.w * kf.x; acc[3][1] += zf.w * kf.y; acc[3][2] += zf.w * kf.z; acc[3][3] += zf.w * kf.w;
  }

  // --- phase 4: transpose via LDS, coalesced stores ---
  __syncthreads();                             // kern + slab fully consumed
#pragma unroll
  for (int oi = 0; oi < 4; ++oi)
#pragma unroll
    for (int d = 0; d < 4; ++d)
      lds[(o_l + oi) * 65 + px_l * 4 + d] = acc[oi][d];
  __syncthreads();

  const int ol2 = tid >> 2, q = tid & 3;       // thread: one o row, quarter
  const int o = og * 64 + ol2;
  const float bias = bo[o];
  const float* Trow = lds + ol2 * 65;
#pragma unroll
  for (int i = 0; i < 2; ++i) {
    float* row = out + ((size_t)(n * kOUTC + o) * kH2 + (2 * h + i)) * kW2 + 2 * w0;
#pragma unroll
    for (int s = 0; s < 2; ++s) {
      const int xb_ = s * 16 + q * 4;          // x offset in [0,32)
      float4 v;
      v.x = Trow[((xb_ + 0) >> 1) * 4 + i * 2 + ((xb_ + 0) & 1)] + bias;
      v.y = Trow[((xb_ + 1) >> 1) * 4 + i * 2 + ((xb_ + 1) & 1)] + bias;
      v.z = Trow[((xb_ + 2) >> 1) * 4 + i * 2 + ((xb_ + 2) & 1)] + bias;
      v.w = Trow[((xb_ + 3) >> 1) * 4 + i * 2 + ((xb_ + 3) & 1)] + bias;
      *(float4*)(row + xb_) = v;
    }
  }
}

extern "C" void kernel_launch(void* const* d_in, const int* in_sizes, int n_in,
                              void* d_out, int out_size, void* d_ws, size_t ws_size,
                              hipStream_t stream) {
  const float* x  = (const float*)d_in[0];   // (4,256,64,64)
  const float* wd = (const float*)d_in[1];   // (64,256,1,1)
  const float* bd = (const float*)d_in[2];   // (64,)
  const float* we = (const float*)d_in[3];   // (100,64,3,3)
  const float* be = (const float*)d_in[4];   // (100,)
  const float* wo = (const float*)d_in[5];   // (256,256,1,1)
  const float* bo = (const float*)d_in[6];   // (256,)
  float* out = (float*)d_out;                // (4,256,128,128)

  // workspace (all 16B-aligned); enc slot retained but unused:
  float* enc = (float*)d_ws;                          // 1,638,400 f (unused)
  float* zT  = enc + 1638400;                         // 4,734,976 f (padded 68x68)
  __hip_bfloat16* downT = (__hip_bfloat16*)(zT + 4734976);      // 1,115,136 bf16
  unsigned short* Aswz  = (unsigned short*)(downT + (size_t)kN * kTImg); // 64,512
  unsigned short* Awoz  = Aswz + 64512;                          // 81,920

  // 3 dispatches: prep(repacks+halo) -> dz GEMM -> fused tail
  k_prep<<<737, 256, 0, stream>>>(we, Aswz, wd, wo, Awoz, zT, downT);
  k_dzmfma<<<1024, 256, 0, stream>>>(x, Awoz, bd, downT, zT);
  k_tail<<<4096, 256, 0, stream>>>(zT, downT, Aswz, be, bo, out);
}

// Round 4
// 143.056 us; speedup vs baseline: 1.0954x; 1.0954x over previous
//
#include <hip/hip_runtime.h>
#include <hip/hip_bf16.h>

// CARAFE R10 = R7 structure (146.0 us anchor) + wave-parallel softmax.
//  - k_prep: merged repacks + halo clears (R7, verified).
//  - k_dzmfma: fused down+z GEMM (unchanged, verified).
//  - k_encmfma: enc conv MFMA GEMM (unchanged, verified). Writes RAW enc.
//  - k_fused_out v7: phase 1b softmax parallelized across all 256 threads
//    (4 workers per (px,d) pair, 6-7 taps each, shfl_xor width-4 reduce).
//    Replaces the 64-thread serial version whose ~125 dependent LDS ops
//    (~10k cyc) sat between two barriers on every block's critical path
//    (R9 counters: k_tail latency-bound, MfmaUtil 5%, VALUBusy 22%).
//    R9's enc-fusion REVERTED (4x redundant enc-MFMA per og: +20us).
// Pipeline: 4 dispatches. N=4, H=W=64, INC=256, CM=64, KUP=5, DELTA=2,
// enc_out=100, OUTC=256.

namespace {
constexpr int kN = 4, kH = 64, kW = 64, kINC = 256, kCM = 64;
constexpr int kENC = 100, kH2 = 128, kW2 = 128, kOUTC = 256;
constexpr int kHW = kH * kW;       // 4096
constexpr int kHW2 = kH2 * kW2;    // 16384
constexpr int kPadW = 66;          // 64 + 1 halo (enc 3x3)
constexpr int kTImg = kPadW * kPadW * kCM;    // 278784 (downT per image)
constexpr int kZPad = 68;          // 64 + 2 halo (reassembly 5x5)
constexpr int kZImg = kZPad * kZPad * kOUTC;  // 1183744 (zT per image)
// k_prep thread-range boundaries (all block-aligned except final tail):
constexpr int kPrepRepackEnc = 9 * 7 * 2 * 512;          // 64512  (252 blocks)
constexpr int kPrepRepackWoz = 8 * 20 * 512;             // 81920  (320 blocks)
constexpr int kPrepHaloZ = 4 * 528 * 16;                 // 33792
constexpr int kPrepHaloD = 4 * 260 * 8;                  // 8320
constexpr int kPrepTotal = kPrepRepackEnc + kPrepRepackWoz + kPrepHaloZ + kPrepHaloD; // 188544
}

typedef __attribute__((ext_vector_type(8))) short short8;   // 8 bf16
typedef __attribute__((ext_vector_type(4))) float floatx4;  // MFMA acc

static __device__ __forceinline__ unsigned short bf16bits(float f) {
  __hip_bfloat16 h = __float2bfloat16(f);
  return *(unsigned short*)&h;
}

// ---------- merged prep: weight repacks + halo clears (one dispatch) ----------
__global__ __launch_bounds__(256) void k_prep(
    const float* __restrict__ we, unsigned short* __restrict__ Aswz,
    const float* __restrict__ wd, const float* __restrict__ wo,
    unsigned short* __restrict__ Awoz,
    float* __restrict__ zT, __hip_bfloat16* __restrict__ downT) {
  const int t = blockIdx.x * 256 + threadIdx.x;
  if (t < kPrepRepackEnc) {
    const int e = t;
    const int j = e & 7, lane = (e >> 3) & 63, kh = (e >> 9) & 1, tm = e >> 10;
    const int mt = tm % 7, tap = tm / 7;
    const int o = mt * 16 + (lane & 15);
    const int ci = kh * 32 + ((lane >> 4) & 3) * 8 + j;
    const float v = (o < kENC) ? we[(size_t)o * 576 + ci * 9 + tap] : 0.f;
    Aswz[e] = bf16bits(v);
  } else if (t < kPrepRepackEnc + kPrepRepackWoz) {
    const int e = t - kPrepRepackEnc;
    const int j = e & 7, lane = (e >> 3) & 63;
    const int rest = e >> 9;
    const int mt = rest % 20, ks = rest / 20;
    const int r = mt * 16 + (lane & 15);
    const int k = ks * 32 + (lane >> 4) * 8 + j;
    const float v = (r < kCM) ? wd[(size_t)r * kINC + k]
                              : wo[(size_t)(r - kCM) * kINC + k];
    Awoz[e] = bf16bits(v);
  } else if (t < kPrepTotal) {
    const int u0 = t - (kPrepRepackEnc + kPrepRepackWoz);
    if (u0 < kPrepHaloZ) {
      const int chunk = u0 & 15, rest = u0 >> 4;
      const int i = rest % 528, n = rest / 528;
      int r, c;
      if (i < 272) { r = i / 68; if (r >= 2) r += 64; c = i % 68; }
      else { const int j = i - 272; r = 2 + (j >> 2); const int cc = j & 3; c = (cc < 2) ? cc : cc + 64; }
      float4* p = (float4*)(zT + (size_t)n * kZImg + ((size_t)r * kZPad + c) * kOUTC) + chunk;
      *p = make_float4(0.f, 0.f, 0.f, 0.f);
    } else {
      const int u = u0 - kPrepHaloZ;
      const int chunk = u & 7, rest = u >> 3;
      const int i = rest % 260, n = rest / 260;
      int r, c;
      if (i < 132) { r = (i / 66) ? 65 : 0; c = i % 66; }
      else { const int j = i - 132; r = 1 + (j >> 1); c = (j & 1) ? 65 : 0; }
      float4* p = (float4*)((char*)downT
                  + ((size_t)n * kTImg + ((size_t)r * kPadW + c) * kCM) * 2) + chunk;
      *p = make_float4(0.f, 0.f, 0.f, 0.f);
    }
  }
}

// ---------- fused down + z GEMM: M=320, K=256, N=16384 (R5, verified) ----------
__global__ __launch_bounds__(256) void k_dzmfma(
    const float* __restrict__ x, const unsigned short* __restrict__ Awoz,
    const float* __restrict__ bd, __hip_bfloat16* __restrict__ downT,
    float* __restrict__ zT) {
  const int b = blockIdx.x;
  const int pt = b & 255, n = b >> 8;
  const int wave = threadIdx.x >> 6, lane = threadIdx.x & 63;
  const int col = lane & 15, quad = lane >> 4;
  const int px = pt * 16 + col;
  const int h = px >> 6, w = px & 63;
  const float* xb = x + (size_t)n * kINC * kHW + px;

  floatx4 acc[5];
#pragma unroll
  for (int m = 0; m < 5; ++m) acc[m] = (floatx4){0.f, 0.f, 0.f, 0.f};

#pragma unroll
  for (int ks = 0; ks < 8; ++ks) {
    float xv[8];
#pragma unroll
    for (int j = 0; j < 8; ++j)
      xv[j] = xb[(size_t)(ks * 32 + quad * 8 + j) * kHW];
    short8 bf;
#pragma unroll
    for (int j = 0; j < 8; ++j) bf[j] = (short)bf16bits(xv[j]);
#pragma unroll
    for (int m = 0; m < 5; ++m) {
      const int wtile = wave * 5 + m;
      const short8 af = *(const short8*)(
          Awoz + ((size_t)(ks * 20 + wtile) * 64 + lane) * 8);
      acc[m] = __builtin_amdgcn_mfma_f32_16x16x32_bf16(af, bf, acc[m], 0, 0, 0);
    }
  }

#pragma unroll
  for (int m = 0; m < 5; ++m) {
    const int wtile = wave * 5 + m;
    const int r0 = wtile * 16 + quad * 4;
    if (wtile < 4) {
      union { unsigned short u[4]; uint2 v; } pk;
#pragma unroll
      for (int rr = 0; rr < 4; ++rr)
        pk.u[rr] = bf16bits(acc[m][rr] + bd[r0 + rr]);
      __hip_bfloat16* dst = downT + (size_t)n * kTImg
                            + ((h + 1) * kPadW + (w + 1)) * kCM + r0;
      *(uint2*)dst = pk.v;
    } else {
      const int o = r0 - kCM;
      float* dst = zT + (size_t)n * kZImg
                   + ((h + 2) * kZPad + (w + 2)) * kOUTC + o;
      *(float4*)dst = make_float4(acc[m][0], acc[m][1], acc[m][2], acc[m][3]);
    }
  }
}

// ---------- enc conv as MFMA GEMM -> enc fp32 (N,100,64,64) (R4, verified) ----------
// Writes RAW (pre-softmax) enc; softmax happens inside k_fused_out.
__global__ __launch_bounds__(256) void k_encmfma(
    const __hip_bfloat16* __restrict__ downT,
    const unsigned short* __restrict__ Aswz,
    const float* __restrict__ be, float* __restrict__ enc) {
  const int b = blockIdx.x;                 // 1024: h(64) x mtp(4) x n(4)
  const int h = b & 63, mtp = (b >> 6) & 3, n = b >> 8;
  const int wave = threadIdx.x >> 6, lane = threadIdx.x & 63;
  const int w0 = wave << 4;
  const int col = lane & 15, quad = lane >> 4;
  const int mt0 = mtp * 2;
  const bool has2 = (mt0 + 1) < 7;
  const short* dT = (const short*)downT + (size_t)n * kTImg;
  floatx4 acc0 = {0.f, 0.f, 0.f, 0.f}, acc1 = {0.f, 0.f, 0.f, 0.f};
#pragma unroll
  for (int tap = 0; tap < 9; ++tap) {
    const int dh = tap / 3 - 1, dw = tap % 3 - 1;
    const int rowbase = ((h + 1 + dh) * kPadW + (w0 + col + 1 + dw)) * kCM
                        + quad * 8;
#pragma unroll
    for (int kh = 0; kh < 2; ++kh) {
      const short8 bf = *(const short8*)(dT + rowbase + kh * 32);
      const short8 a0 = *(const short8*)(
          Aswz + (((size_t)(tap * 7 + mt0) * 2 + kh) * 64 + lane) * 8);
      acc0 = __builtin_amdgcn_mfma_f32_16x16x32_bf16(a0, bf, acc0, 0, 0, 0);
      if (has2) {
        const short8 a1 = *(const short8*)(
            Aswz + (((size_t)(tap * 7 + mt0 + 1) * 2 + kh) * 64 + lane) * 8);
        acc1 = __builtin_amdgcn_mfma_f32_16x16x32_bf16(a1, bf, acc1, 0, 0, 0);
      }
    }
  }
  const int p = h * kW + w0 + col;
#pragma unroll
  for (int r = 0; r < 4; ++r) {
    const int o = mt0 * 16 + quad * 4 + r;
    if (o < kENC) enc[(size_t)(n * kENC + o) * kHW + p] = acc0[r] + be[o];
  }
  if (has2) {
#pragma unroll
    for (int r = 0; r < 4; ++r) {
      const int o = (mt0 + 1) * 16 + quad * 4 + r;
      if (o < kENC) enc[(size_t)(n * kENC + o) * kHW + p] = acc1[r] + be[o];
    }
  }
}

// ---------- fused softmax + reassembly + pixel shuffle + bias -> out (v7) ----------
// 4096 blocks: pt(256) x og(4) x n(4); 256 thr = 4 waves.
// Block tile: 16 px (one h row segment) x 64 o x 4 d.
// Phase 1a: stage RAW kern[16 px][100 ch] in LDS (coalesced).
// Phase 1b: WAVE-PARALLEL softmax: 64 (px,d) pairs x 4 workers; each worker
//   6-7 taps in regs; shfl_xor width-4 reduce for max and sum. 14 LDS ops
//   per worker (was 125 serial on 64 threads).
// Phase 2: 25 taps: z float4 direct from global (L1-served) + kern ds_read.
// Phase 3: acc -> LDS transpose (stride-65 pad) -> coalesced float4 stores.
__global__ __launch_bounds__(256) void k_fused_out(
    const float* __restrict__ zT, const float* __restrict__ enc,
    const float* __restrict__ bo, float* __restrict__ out) {
  const int b = blockIdx.x;
  const int pt = b & 255, og = (b >> 8) & 3, n = b >> 10;
  const int tid = threadIdx.x;
  const int wave = tid >> 6, lane = tid & 63;
  const int h = pt >> 2, w0 = (pt & 3) << 4;   // 16-px segment [w0, w0+16)
  const int px0 = pt * 16;                     // linear px base

  __shared__ float lds[64 * 65];               // 16.6 KB; kern tile then acc^T
  float* kernLDS = lds;                        // [16 px][104] (pad 100->104)

  // --- phase 1a: stage raw kern tile ---
  {
    const int p = tid & 15, chb = tid >> 4;
#pragma unroll
    for (int r = 0; r < 7; ++r) {
      const int ch = r * 16 + chb;
      if (ch < kENC)
        kernLDS[p * 104 + ch] = enc[((size_t)n * kENC + ch) * kHW + px0 + p];
    }
  }
  __syncthreads();

  // --- phase 1b: wave-parallel softmax over 25 taps ---
  // worker: pair = (px,d), q = tid&3 handles taps [start, start+count).
  // q=0: 0..6 (7), q=1: 7..12, q=2: 13..18, q=3: 19..24 (6 each).
  {
    const int pair = tid >> 2, q = tid & 3;
    const int p = pair >> 2, d = pair & 3;
    float* kb = kernLDS + p * 104 + d;         // taps at stride 4 floats
    const int start = q ? (1 + 6 * q) : 0;
    const int count = q ? 6 : 7;
    float v[7];
    float m = -1e30f;
#pragma unroll
    for (int k = 0; k < 7; ++k)
      if (k < count) { v[k] = kb[(start + k) * 4]; m = fmaxf(m, v[k]); }
    m = fmaxf(m, __shfl_xor(m, 1));
    m = fmaxf(m, __shfl_xor(m, 2));
    float s = 0.f;
#pragma unroll
    for (int k = 0; k < 7; ++k)
      if (k < count) { v[k] = __expf(v[k] - m); s += v[k]; }
    s += __shfl_xor(s, 1);
    s += __shfl_xor(s, 2);
    const float inv = 1.f / s;
#pragma unroll
    for (int k = 0; k < 7; ++k)
      if (k < count) kb[(start + k) * 4] = v[k] * inv;
  }
  __syncthreads();

  // --- phase 2: 25 taps ---
  const int oc = lane & 15, pxi = lane >> 4;
  const int px_l = wave * 4 + pxi;             // [0,16)
  const int w = w0 + px_l;
  const int o_l = oc * 4;                      // [0,64) step 4
  const float* zb = zT + (size_t)n * kZImg + og * 64 + o_l;
  const float* kp = kernLDS + px_l * 104;
  float acc[4][4] = {};                        // [oi][d]
#pragma unroll
  for (int tap = 0; tap < 25; ++tap) {
    const int kh = tap / 5, kw = tap % 5;      // z idx: (h+2 + kh-2) = h+kh
    const float4 zf = *(const float4*)(
        zb + ((size_t)(h + kh) * kZPad + (w + kw)) * kOUTC);
    const float4 kf = *(const float4*)(kp + tap * 4);
    acc[0][0] += zf.x * kf.x; acc[0][1] += zf.x * kf.y; acc[0][2] += zf.x * kf.z; acc[0][3] += zf.x * kf.w;
    acc[1][0] += zf.y * kf.x; acc[1][1] += zf.y * kf.y; acc[1][2] += zf.y * kf.z; acc[1][3] += zf.y * kf.w;
    acc[2][0] += zf.z * kf.x; acc[2][1] += zf.z * kf.y; acc[2][2] += zf.z * kf.z; acc[2][3] += zf.z * kf.w;
    acc[3][0] += zf.w * kf.x; acc[3][1] += zf.w * kf.y; acc[3][2] += zf.w * kf.z; acc[3][3] += zf.w * kf.w;
  }

  // --- phase 3: transpose via LDS, coalesced stores ---
  __syncthreads();                             // kern tile fully consumed
#pragma unroll
  for (int oi = 0; oi < 4; ++oi)
#pragma unroll
    for (int d = 0; d < 4; ++d)
      lds[(o_l + oi) * 65 + px_l * 4 + d] = acc[oi][d];
  __syncthreads();

  const int ol2 = tid >> 2, q = tid & 3;       // thread: one o row, quarter
  const int o = og * 64 + ol2;
  const float bias = bo[o];
  const float* Trow = lds + ol2 * 65;
#pragma unroll
  for (int i = 0; i < 2; ++i) {
    float* row = out + ((size_t)(n * kOUTC + o) * kH2 + (2 * h + i)) * kW2 + 2 * w0;
#pragma unroll
    for (int s = 0; s < 2; ++s) {
      const int xb_ = s * 16 + q * 4;          // x offset in [0,32)
      float4 v;
      v.x = Trow[((xb_ + 0) >> 1) * 4 + i * 2 + ((xb_ + 0) & 1)] + bias;
      v.y = Trow[((xb_ + 1) >> 1) * 4 + i * 2 + ((xb_ + 1) & 1)] + bias;
      v.z = Trow[((xb_ + 2) >> 1) * 4 + i * 2 + ((xb_ + 2) & 1)] + bias;
      v.w = Trow[((xb_ + 3) >> 1) * 4 + i * 2 + ((xb_ + 3) & 1)] + bias;
      *(float4*)(row + xb_) = v;
    }
  }
}

extern "C" void kernel_launch(void* const* d_in, const int* in_sizes, int n_in,
                              void* d_out, int out_size, void* d_ws, size_t ws_size,
                              hipStream_t stream) {
  const float* x  = (const float*)d_in[0];   // (4,256,64,64)
  const float* wd = (const float*)d_in[1];   // (64,256,1,1)
  const float* bd = (const float*)d_in[2];   // (64,)
  const float* we = (const float*)d_in[3];   // (100,64,3,3)
  const float* be = (const float*)d_in[4];   // (100,)
  const float* wo = (const float*)d_in[5];   // (256,256,1,1)
  const float* bo = (const float*)d_in[6];   // (256,)
  float* out = (float*)d_out;                // (4,256,128,128)

  // workspace (all 16B-aligned):
  float* enc = (float*)d_ws;                          // 1,638,400 f
  float* zT  = enc + 1638400;                         // 4,734,976 f (padded 68x68)
  __hip_bfloat16* downT = (__hip_bfloat16*)(zT + 4734976);      // 1,115,136 bf16
  unsigned short* Aswz  = (unsigned short*)(downT + (size_t)kN * kTImg); // 64,512
  unsigned short* Awoz  = Aswz + 64512;                          // 81,920

  // 4 dispatches: prep(repacks+halo) -> dz GEMM -> enc GEMM -> fused out
  k_prep<<<737, 256, 0, stream>>>(we, Aswz, wd, wo, Awoz, zT, downT);
  k_dzmfma<<<1024, 256, 0, stream>>>(x, Awoz, bd, downT, zT);
  k_encmfma<<<1024, 256, 0, stream>>>(downT, Aswz, be, enc);
  k_fused_out<<<4096, 256, 0, stream>>>(zT, enc, bo, out);
}

// Round 5
// 141.590 us; speedup vs baseline: 1.1068x; 1.0104x over previous
//
#include <hip/hip_runtime.h>
#include <hip/hip_bf16.h>

// CARAFE R11 = R10 (143.1 us anchor) + two bitwise-neutral scheduling fixes:
//  - k_dzmfma v2: x-tile staged in LDS as bf16 ONCE per block (was: all 4
//    waves redundantly issuing the identical 64 global loads + 64 cvts per
//    thread). Each wave loads its 2 ksteps, ds_write_b128; MFMA loop reads
//    ds_read_b128 (pitch 264 shorts -> 2-way bank alias, free).
//  - k_fused_out v8: 2 og per block (2048 blocks: pt x oh x n). Kern tile
//    staged + softmaxed once, reused for both og. LDS 23.3 KB (kern 1664f +
//    transpose scratch 4160f) -> 6 blocks/CU.
//  - k_prep, k_encmfma unchanged (verified).
// Same arithmetic values & order everywhere -> absmax must stay 0.015625.
// Pipeline: 4 dispatches. N=4, H=W=64, INC=256, CM=64, KUP=5, DELTA=2,
// enc_out=100, OUTC=256.

namespace {
constexpr int kN = 4, kH = 64, kW = 64, kINC = 256, kCM = 64;
constexpr int kENC = 100, kH2 = 128, kW2 = 128, kOUTC = 256;
constexpr int kHW = kH * kW;       // 4096
constexpr int kHW2 = kH2 * kW2;    // 16384
constexpr int kPadW = 66;          // 64 + 1 halo (enc 3x3)
constexpr int kTImg = kPadW * kPadW * kCM;    // 278784 (downT per image)
constexpr int kZPad = 68;          // 64 + 2 halo (reassembly 5x5)
constexpr int kZImg = kZPad * kZPad * kOUTC;  // 1183744 (zT per image)
constexpr int kXP = 264;           // x-tile LDS pitch in shorts (132 words ->
                                   // 4-bank stride -> 2-way alias, free)
// k_prep thread-range boundaries (all block-aligned except final tail):
constexpr int kPrepRepackEnc = 9 * 7 * 2 * 512;          // 64512  (252 blocks)
constexpr int kPrepRepackWoz = 8 * 20 * 512;             // 81920  (320 blocks)
constexpr int kPrepHaloZ = 4 * 528 * 16;                 // 33792
constexpr int kPrepHaloD = 4 * 260 * 8;                  // 8320
constexpr int kPrepTotal = kPrepRepackEnc + kPrepRepackWoz + kPrepHaloZ + kPrepHaloD; // 188544
}

typedef __attribute__((ext_vector_type(8))) short short8;   // 8 bf16
typedef __attribute__((ext_vector_type(4))) float floatx4;  // MFMA acc

static __device__ __forceinline__ unsigned short bf16bits(float f) {
  __hip_bfloat16 h = __float2bfloat16(f);
  return *(unsigned short*)&h;
}

// ---------- merged prep: weight repacks + halo clears (one dispatch) ----------
__global__ __launch_bounds__(256) void k_prep(
    const float* __restrict__ we, unsigned short* __restrict__ Aswz,
    const float* __restrict__ wd, const float* __restrict__ wo,
    unsigned short* __restrict__ Awoz,
    float* __restrict__ zT, __hip_bfloat16* __restrict__ downT) {
  const int t = blockIdx.x * 256 + threadIdx.x;
  if (t < kPrepRepackEnc) {
    const int e = t;
    const int j = e & 7, lane = (e >> 3) & 63, kh = (e >> 9) & 1, tm = e >> 10;
    const int mt = tm % 7, tap = tm / 7;
    const int o = mt * 16 + (lane & 15);
    const int ci = kh * 32 + ((lane >> 4) & 3) * 8 + j;
    const float v = (o < kENC) ? we[(size_t)o * 576 + ci * 9 + tap] : 0.f;
    Aswz[e] = bf16bits(v);
  } else if (t < kPrepRepackEnc + kPrepRepackWoz) {
    const int e = t - kPrepRepackEnc;
    const int j = e & 7, lane = (e >> 3) & 63;
    const int rest = e >> 9;
    const int mt = rest % 20, ks = rest / 20;
    const int r = mt * 16 + (lane & 15);
    const int k = ks * 32 + (lane >> 4) * 8 + j;
    const float v = (r < kCM) ? wd[(size_t)r * kINC + k]
                              : wo[(size_t)(r - kCM) * kINC + k];
    Awoz[e] = bf16bits(v);
  } else if (t < kPrepTotal) {
    const int u0 = t - (kPrepRepackEnc + kPrepRepackWoz);
    if (u0 < kPrepHaloZ) {
      const int chunk = u0 & 15, rest = u0 >> 4;
      const int i = rest % 528, n = rest / 528;
      int r, c;
      if (i < 272) { r = i / 68; if (r >= 2) r += 64; c = i % 68; }
      else { const int j = i - 272; r = 2 + (j >> 2); const int cc = j & 3; c = (cc < 2) ? cc : cc + 64; }
      float4* p = (float4*)(zT + (size_t)n * kZImg + ((size_t)r * kZPad + c) * kOUTC) + chunk;
      *p = make_float4(0.f, 0.f, 0.f, 0.f);
    } else {
      const int u = u0 - kPrepHaloZ;
      const int chunk = u & 7, rest = u >> 3;
      const int i = rest % 260, n = rest / 260;
      int r, c;
      if (i < 132) { r = (i / 66) ? 65 : 0; c = i % 66; }
      else { const int j = i - 132; r = 1 + (j >> 1); c = (j & 1) ? 65 : 0; }
      float4* p = (float4*)((char*)downT
                  + ((size_t)n * kTImg + ((size_t)r * kPadW + c) * kCM) * 2) + chunk;
      *p = make_float4(0.f, 0.f, 0.f, 0.f);
    }
  }
}

// ---------- fused down + z GEMM: M=320, K=256, N=16384 (v2) ----------
// x-tile (16 px x 256 ch) staged in LDS as bf16 once per block; each wave
// loads only ks = {2*wave, 2*wave+1} (16 loads + 16 cvts/thread, was 64+64).
// Same bf16 values + same MFMA order as v1 -> bitwise identical output.
__global__ __launch_bounds__(256) void k_dzmfma(
    const float* __restrict__ x, const unsigned short* __restrict__ Awoz,
    const float* __restrict__ bd, __hip_bfloat16* __restrict__ downT,
    float* __restrict__ zT) {
  const int b = blockIdx.x;
  const int pt = b & 255, n = b >> 8;
  const int wave = threadIdx.x >> 6, lane = threadIdx.x & 63;
  const int col = lane & 15, quad = lane >> 4;
  const int px = pt * 16 + col;
  const int h = px >> 6, w = px & 63;

  __shared__ unsigned short xlds[16 * kXP];    // [px][ch] bf16, 8448 B

  // --- stage x tile: wave w handles ksteps {2w, 2w+1} ---
  {
    const float* xb = x + (size_t)n * kINC * kHW + px;
#pragma unroll
    for (int ki = 0; ki < 2; ++ki) {
      const int ks = wave * 2 + ki;
      float xv[8];
#pragma unroll
      for (int j = 0; j < 8; ++j)
        xv[j] = xb[(size_t)(ks * 32 + quad * 8 + j) * kHW];
      short8 bf;
#pragma unroll
      for (int j = 0; j < 8; ++j) bf[j] = (short)bf16bits(xv[j]);
      *(short8*)(xlds + col * kXP + ks * 32 + quad * 8) = bf;
    }
  }
  __syncthreads();

  floatx4 acc[5];
#pragma unroll
  for (int m = 0; m < 5; ++m) acc[m] = (floatx4){0.f, 0.f, 0.f, 0.f};

#pragma unroll
  for (int ks = 0; ks < 8; ++ks) {
    const short8 bf = *(const short8*)(xlds + col * kXP + ks * 32 + quad * 8);
#pragma unroll
    for (int m = 0; m < 5; ++m) {
      const int wtile = wave * 5 + m;
      const short8 af = *(const short8*)(
          Awoz + ((size_t)(ks * 20 + wtile) * 64 + lane) * 8);
      acc[m] = __builtin_amdgcn_mfma_f32_16x16x32_bf16(af, bf, acc[m], 0, 0, 0);
    }
  }

#pragma unroll
  for (int m = 0; m < 5; ++m) {
    const int wtile = wave * 5 + m;
    const int r0 = wtile * 16 + quad * 4;
    if (wtile < 4) {
      union { unsigned short u[4]; uint2 v; } pk;
#pragma unroll
      for (int rr = 0; rr < 4; ++rr)
        pk.u[rr] = bf16bits(acc[m][rr] + bd[r0 + rr]);
      __hip_bfloat16* dst = downT + (size_t)n * kTImg
                            + ((h + 1) * kPadW + (w + 1)) * kCM + r0;
      *(uint2*)dst = pk.v;
    } else {
      const int o = r0 - kCM;
      float* dst = zT + (size_t)n * kZImg
                   + ((h + 2) * kZPad + (w + 2)) * kOUTC + o;
      *(float4*)dst = make_float4(acc[m][0], acc[m][1], acc[m][2], acc[m][3]);
    }
  }
}

// ---------- enc conv as MFMA GEMM -> enc fp32 (N,100,64,64) (R4, verified) ----------
// Writes RAW (pre-softmax) enc; softmax happens inside k_fused_out.
__global__ __launch_bounds__(256) void k_encmfma(
    const __hip_bfloat16* __restrict__ downT,
    const unsigned short* __restrict__ Aswz,
    const float* __restrict__ be, float* __restrict__ enc) {
  const int b = blockIdx.x;                 // 1024: h(64) x mtp(4) x n(4)
  const int h = b & 63, mtp = (b >> 6) & 3, n = b >> 8;
  const int wave = threadIdx.x >> 6, lane = threadIdx.x & 63;
  const int w0 = wave << 4;
  const int col = lane & 15, quad = lane >> 4;
  const int mt0 = mtp * 2;
  const bool has2 = (mt0 + 1) < 7;
  const short* dT = (const short*)downT + (size_t)n * kTImg;
  floatx4 acc0 = {0.f, 0.f, 0.f, 0.f}, acc1 = {0.f, 0.f, 0.f, 0.f};
#pragma unroll
  for (int tap = 0; tap < 9; ++tap) {
    const int dh = tap / 3 - 1, dw = tap % 3 - 1;
    const int rowbase = ((h + 1 + dh) * kPadW + (w0 + col + 1 + dw)) * kCM
                        + quad * 8;
#pragma unroll
    for (int kh = 0; kh < 2; ++kh) {
      const short8 bf = *(const short8*)(dT + rowbase + kh * 32);
      const short8 a0 = *(const short8*)(
          Aswz + (((size_t)(tap * 7 + mt0) * 2 + kh) * 64 + lane) * 8);
      acc0 = __builtin_amdgcn_mfma_f32_16x16x32_bf16(a0, bf, acc0, 0, 0, 0);
      if (has2) {
        const short8 a1 = *(const short8*)(
            Aswz + (((size_t)(tap * 7 + mt0 + 1) * 2 + kh) * 64 + lane) * 8);
        acc1 = __builtin_amdgcn_mfma_f32_16x16x32_bf16(a1, bf, acc1, 0, 0, 0);
      }
    }
  }
  const int p = h * kW + w0 + col;
#pragma unroll
  for (int r = 0; r < 4; ++r) {
    const int o = mt0 * 16 + quad * 4 + r;
    if (o < kENC) enc[(size_t)(n * kENC + o) * kHW + p] = acc0[r] + be[o];
  }
  if (has2) {
#pragma unroll
    for (int r = 0; r < 4; ++r) {
      const int o = (mt0 + 1) * 16 + quad * 4 + r;
      if (o < kENC) enc[(size_t)(n * kENC + o) * kHW + p] = acc1[r] + be[o];
    }
  }
}

// ---------- fused softmax + reassembly + pixel shuffle + bias -> out (v8) ----------
// 2048 blocks: pt(256) x oh(2) x n(4); 256 thr = 4 waves. Each block does
// og = {2*oh, 2*oh+1}: kern tile staged + softmaxed ONCE, reused for both.
// Phase 1a: stage RAW kern[16 px][100 ch] in LDS (coalesced).
// Phase 1b: wave-parallel softmax (64 (px,d) pairs x 4 workers, shfl_xor).
// Per og: phase 2 (25 taps: global z float4 + kern ds_read) -> sync ->
//   transpose via scratch (stride-65) -> sync -> coalesced float4 stores.
__global__ __launch_bounds__(256) void k_fused_out(
    const float* __restrict__ zT, const float* __restrict__ enc,
    const float* __restrict__ bo, float* __restrict__ out) {
  const int b = blockIdx.x;
  const int pt = b & 255, oh = (b >> 8) & 1, n = b >> 9;
  const int tid = threadIdx.x;
  const int wave = tid >> 6, lane = tid & 63;
  const int h = pt >> 2, w0 = (pt & 3) << 4;   // 16-px segment [w0, w0+16)
  const int px0 = pt * 16;                     // linear px base

  __shared__ float lds[1664 + 4160];           // 23.3 KB
  float* kernLDS = lds;                        // [16 px][104] (pad 100->104)
  float* scr = lds + 1664;                     // transpose scratch [64][65]

  // --- phase 1a: stage raw kern tile ---
  {
    const int p = tid & 15, chb = tid >> 4;
#pragma unroll
    for (int r = 0; r < 7; ++r) {
      const int ch = r * 16 + chb;
      if (ch < kENC)
        kernLDS[p * 104 + ch] = enc[((size_t)n * kENC + ch) * kHW + px0 + p];
    }
  }
  __syncthreads();

  // --- phase 1b: wave-parallel softmax over 25 taps ---
  {
    const int pair = tid >> 2, q = tid & 3;
    const int p = pair >> 2, d = pair & 3;
    float* kb = kernLDS + p * 104 + d;         // taps at stride 4 floats
    const int start = q ? (1 + 6 * q) : 0;
    const int count = q ? 6 : 7;
    float v[7];
    float m = -1e30f;
#pragma unroll
    for (int k = 0; k < 7; ++k)
      if (k < count) { v[k] = kb[(start + k) * 4]; m = fmaxf(m, v[k]); }
    m = fmaxf(m, __shfl_xor(m, 1));
    m = fmaxf(m, __shfl_xor(m, 2));
    float s = 0.f;
#pragma unroll
    for (int k = 0; k < 7; ++k)
      if (k < count) { v[k] = __expf(v[k] - m); s += v[k]; }
    s += __shfl_xor(s, 1);
    s += __shfl_xor(s, 2);
    const float inv = 1.f / s;
#pragma unroll
    for (int k = 0; k < 7; ++k)
      if (k < count) kb[(start + k) * 4] = v[k] * inv;
  }
  __syncthreads();

  const int oc = lane & 15, pxi = lane >> 4;
  const int px_l = wave * 4 + pxi;             // [0,16)
  const int w = w0 + px_l;
  const int o_l = oc * 4;                      // [0,64) step 4
  const float* kp = kernLDS + px_l * 104;
  const int ol2 = tid >> 2, q2 = tid & 3;      // store-phase mapping

#pragma unroll
  for (int ogi = 0; ogi < 2; ++ogi) {
    const int og = oh * 2 + ogi;

    // --- phase 2: 25 taps, z direct from global (L1/L2-served) ---
    const float* zb = zT + (size_t)n * kZImg + og * 64 + o_l;
    float acc[4][4] = {};                      // [oi][d]
#pragma unroll
    for (int tap = 0; tap < 25; ++tap) {
      const int kh = tap / 5, kw = tap % 5;    // z idx: (h+2 + kh-2) = h+kh
      const float4 zf = *(const float4*)(
          zb + ((size_t)(h + kh) * kZPad + (w + kw)) * kOUTC);
      const float4 kf = *(const float4*)(kp + tap * 4);
      acc[0][0] += zf.x * kf.x; acc[0][1] += zf.x * kf.y; acc[0][2] += zf.x * kf.z; acc[0][3] += zf.x * kf.w;
      acc[1][0] += zf.y * kf.x; acc[1][1] += zf.y * kf.y; acc[1][2] += zf.y * kf.z; acc[1][3] += zf.y * kf.w;
      acc[2][0] += zf.z * kf.x; acc[2][1] += zf.z * kf.y; acc[2][2] += zf.z * kf.z; acc[2][3] += zf.z * kf.w;
      acc[3][0] += zf.w * kf.x; acc[3][1] += zf.w * kf.y; acc[3][2] += zf.w * kf.z; acc[3][3] += zf.w * kf.w;
    }

    // --- phase 3: transpose via scratch, coalesced stores ---
    __syncthreads();                           // scratch free (prev stores done)
#pragma unroll
    for (int oi = 0; oi < 4; ++oi)
#pragma unroll
      for (int d = 0; d < 4; ++d)
        scr[(o_l + oi) * 65 + px_l * 4 + d] = acc[oi][d];
    __syncthreads();

    const int o = og * 64 + ol2;
    const float bias = bo[o];
    const float* Trow = scr + ol2 * 65;
#pragma unroll
    for (int i = 0; i < 2; ++i) {
      float* row = out + ((size_t)(n * kOUTC + o) * kH2 + (2 * h + i)) * kW2 + 2 * w0;
#pragma unroll
      for (int s = 0; s < 2; ++s) {
        const int xb_ = s * 16 + q2 * 4;       // x offset in [0,32)
        float4 v;
        v.x = Trow[((xb_ + 0) >> 1) * 4 + i * 2 + ((xb_ + 0) & 1)] + bias;
        v.y = Trow[((xb_ + 1) >> 1) * 4 + i * 2 + ((xb_ + 1) & 1)] + bias;
        v.z = Trow[((xb_ + 2) >> 1) * 4 + i * 2 + ((xb_ + 2) & 1)] + bias;
        v.w = Trow[((xb_ + 3) >> 1) * 4 + i * 2 + ((xb_ + 3) & 1)] + bias;
        *(float4*)(row + xb_) = v;
      }
    }
  }
}

extern "C" void kernel_launch(void* const* d_in, const int* in_sizes, int n_in,
                              void* d_out, int out_size, void* d_ws, size_t ws_size,
                              hipStream_t stream) {
  const float* x  = (const float*)d_in[0];   // (4,256,64,64)
  const float* wd = (const float*)d_in[1];   // (64,256,1,1)
  const float* bd = (const float*)d_in[2];   // (64,)
  const float* we = (const float*)d_in[3];   // (100,64,3,3)
  const float* be = (const float*)d_in[4];   // (100,)
  const float* wo = (const float*)d_in[5];   // (256,256,1,1)
  const float* bo = (const float*)d_in[6];   // (256,)
  float* out = (float*)d_out;                // (4,256,128,128)

  // workspace (all 16B-aligned):
  float* enc = (float*)d_ws;                          // 1,638,400 f
  float* zT  = enc + 1638400;                         // 4,734,976 f (padded 68x68)
  __hip_bfloat16* downT = (__hip_bfloat16*)(zT + 4734976);      // 1,115,136 bf16
  unsigned short* Aswz  = (unsigned short*)(downT + (size_t)kN * kTImg); // 64,512
  unsigned short* Awoz  = Aswz + 64512;                          // 81,920

  // 4 dispatches: prep(repacks+halo) -> dz GEMM -> enc GEMM -> fused out
  k_prep<<<737, 256, 0, stream>>>(we, Aswz, wd, wo, Awoz, zT, downT);
  k_dzmfma<<<1024, 256, 0, stream>>>(x, Awoz, bd, downT, zT);
  k_encmfma<<<1024, 256, 0, stream>>>(downT, Aswz, be, enc);
  k_fused_out<<<2048, 256, 0, stream>>>(zT, enc, bo, out);
}